// Round 1
// baseline (483.891 us; speedup 1.0000x reference)
//
#include <hip/hip_runtime.h>

// MultiResolutionHashEncoding: N=524288 pts, L=16 levels, F=2, T=2^19.
// One thread per (point, level). tid = p*16 + l; out as float2* -> out[tid].
//
// Scalings floor(16*growth^l) precomputed with f32 semantics of the reference
// (growth rounds DOWN in f32 => level 15 scaling is 2047, not 2048).
__device__ __constant__ float c_scal[16] = {
    16.f, 22.f, 30.f, 42.f, 58.f, 80.f, 111.f, 153.f,
    212.f, 294.f, 406.f, 561.f, 776.f, 1072.f, 1482.f, 2047.f
};

#define TBL_T 524288u   // 2^19 entries per level
#define NPTS  524288

__global__ __launch_bounds__(256) void hashenc_kernel(
        const float* __restrict__ x,
        const float2* __restrict__ tbl,
        float2* __restrict__ out) {
    unsigned tid = blockIdx.x * 256u + threadIdx.x;
    unsigned p = tid >> 4;    // point index
    unsigned l = tid & 15u;   // level index

    float px = x[p * 3 + 0];
    float py = x[p * 3 + 1];
    float pz = x[p * 3 + 2];

    float s  = c_scal[l];
    float sx = px * s, sy = py * s, sz = pz * s;
    float cx = floorf(sx), cy = floorf(sy), cz = floorf(sz);
    float fx = sx - cx, fy = sy - cy, fz = sz - cz;

    unsigned ux = (unsigned)cx, uy = (unsigned)cy, uz = (unsigned)cz;

    // hash components: coord0 * 1, coord1 * 2654435761, coord2 * 805459861
    unsigned hx[2], hy[2], hz[2];
    hx[0] = ux;
    hx[1] = ux + 1u;
    hy[0] = uy * 2654435761u;
    hy[1] = (uy + 1u) * 2654435761u;
    hz[0] = uz * 805459861u;
    hz[1] = (uz + 1u) * 805459861u;

    unsigned base = l * TBL_T;

    unsigned idx[8];
#pragma unroll
    for (int i = 0; i < 8; ++i) {
        unsigned h = hx[(i >> 2) & 1] ^ hy[(i >> 1) & 1] ^ hz[i & 1];
        idx[i] = (h & (TBL_T - 1u)) + base;
    }

    // issue all 8 gathers before consuming
    float2 v[8];
#pragma unroll
    for (int i = 0; i < 8; ++i) v[i] = tbl[idx[i]];

    float wx[2], wy[2], wz[2];
    wx[0] = 1.f - fx; wx[1] = fx;
    wy[0] = 1.f - fy; wy[1] = fy;
    wz[0] = 1.f - fz; wz[1] = fz;

    float o0 = 0.f, o1 = 0.f;
#pragma unroll
    for (int i = 0; i < 8; ++i) {
        float w = (wx[(i >> 2) & 1] * wy[(i >> 1) & 1]) * wz[i & 1];
        o0 += v[i].x * w;
        o1 += v[i].y * w;
    }

    out[tid] = make_float2(o0, o1);
}

extern "C" void kernel_launch(void* const* d_in, const int* in_sizes, int n_in,
                              void* d_out, int out_size, void* d_ws, size_t ws_size,
                              hipStream_t stream) {
    const float*  x   = (const float*)d_in[0];
    const float2* tbl = (const float2*)d_in[1];   // [L*T][F=2] floats
    float2*       out = (float2*)d_out;           // [NPTS][16] float2

    const unsigned total = NPTS * 16u;            // 8,388,608 threads
    const unsigned block = 256u;
    const unsigned grid  = total / block;         // 32768 blocks

    hashenc_kernel<<<grid, block, 0, stream>>>(x, tbl, out);
}

// Round 2
// 366.651 us; speedup vs baseline: 1.3198x; 1.3198x over previous
//
#include <hip/hip_runtime.h>

// MultiResolutionHashEncoding, time-phased by level.
// One thread per point; loop l=0..15 with __syncthreads per level so the
// whole device gathers from ~one 4 MiB level slice at a time (fits per-XCD L2).
// Accumulate all 32 outputs in VGPRs; store 128 B/thread at the end.
//
// Scalings floor(16*growth^l) with f32 semantics of the reference
// (growth rounds DOWN in f32 => level 15 scaling is 2047, not 2048).
__device__ __constant__ float c_scal[16] = {
    16.f, 22.f, 30.f, 42.f, 58.f, 80.f, 111.f, 153.f,
    212.f, 294.f, 406.f, 561.f, 776.f, 1072.f, 1482.f, 2047.f
};

#define TBL_T 524288u   // 2^19 entries per level
#define NPTS  524288u

__global__ __launch_bounds__(256) void hashenc_tp(
        const float* __restrict__ x,
        const float2* __restrict__ tbl,
        float4* __restrict__ out) {
    unsigned p = blockIdx.x * 256u + threadIdx.x;

    float px = x[p * 3 + 0];
    float py = x[p * 3 + 1];
    float pz = x[p * 3 + 2];

    float o[32];

#pragma unroll
    for (int l = 0; l < 16; ++l) {
        float s  = c_scal[l];
        float sx = px * s, sy = py * s, sz = pz * s;
        float cx = floorf(sx), cy = floorf(sy), cz = floorf(sz);
        float fx = sx - cx, fy = sy - cy, fz = sz - cz;

        unsigned ux = (unsigned)cx, uy = (unsigned)cy, uz = (unsigned)cz;

        unsigned hx0 = ux,                    hx1 = ux + 1u;
        unsigned hy0 = uy * 2654435761u,      hy1 = (uy + 1u) * 2654435761u;
        unsigned hz0 = uz * 805459861u,       hz1 = (uz + 1u) * 805459861u;

        unsigned base = (unsigned)l * TBL_T;

        unsigned idx[8];
#pragma unroll
        for (int i = 0; i < 8; ++i) {
            unsigned h = ((i & 4) ? hx1 : hx0) ^ ((i & 2) ? hy1 : hy0)
                       ^ ((i & 1) ? hz1 : hz0);
            idx[i] = (h & (TBL_T - 1u)) + base;
        }

        float2 v[8];
#pragma unroll
        for (int i = 0; i < 8; ++i) v[i] = tbl[idx[i]];

        float wx1 = fx, wx0 = 1.f - fx;
        float wy1 = fy, wy0 = 1.f - fy;
        float wz1 = fz, wz0 = 1.f - fz;

        float o0 = 0.f, o1 = 0.f;
#pragma unroll
        for (int i = 0; i < 8; ++i) {
            float w = (((i & 4) ? wx1 : wx0) * ((i & 2) ? wy1 : wy0))
                    * ((i & 1) ? wz1 : wz0);
            o0 += v[i].x * w;
            o1 += v[i].y * w;
        }
        o[2 * l]     = o0;
        o[2 * l + 1] = o1;

        __syncthreads();   // keep the block's waves phase-locked per level
    }

    // 128 B per point, contiguous: out[p*8 .. p*8+7] as float4
    float4* dst = out + (size_t)p * 8u;
#pragma unroll
    for (int q = 0; q < 8; ++q)
        dst[q] = make_float4(o[4 * q], o[4 * q + 1], o[4 * q + 2], o[4 * q + 3]);
}

extern "C" void kernel_launch(void* const* d_in, const int* in_sizes, int n_in,
                              void* d_out, int out_size, void* d_ws, size_t ws_size,
                              hipStream_t stream) {
    const float*  x   = (const float*)d_in[0];
    const float2* tbl = (const float2*)d_in[1];   // [L*T][F=2] floats
    float4*       out = (float4*)d_out;           // [NPTS][32] floats

    const unsigned block = 256u;
    const unsigned grid  = NPTS / block;          // 2048 blocks, 1 thread/point

    hashenc_tp<<<grid, block, 0, stream>>>(x, tbl, out);
}

// Round 4
// 335.147 us; speedup vs baseline: 1.4438x; 1.0940x over previous
//
#include <hip/hip_runtime.h>

// MultiResolutionHashEncoding, level-phased via SEPARATE KERNEL LAUNCHES.
// Stream ordering = device-wide barrier between levels, so each fine level's
// 4 MiB table slice is the only active read set -> L2-resident per XCD.
// Per-level results go to ws[l][NPTS] (float2, coalesced); final kernel
// transposes to out[NPTS][16] float2.
//
// Scalings floor(16*growth^l) with f32 semantics of the reference
// (growth rounds DOWN in f32 => level 15 scaling is 2047, not 2048).
__device__ __constant__ float c_scal[16] = {
    16.f, 22.f, 30.f, 42.f, 58.f, 80.f, 111.f, 153.f,
    212.f, 294.f, 406.f, 561.f, 776.f, 1072.f, 1482.f, 2047.f
};

#define TBL_T 524288u   // 2^19 entries per level
#define NPTS  524288u

__device__ __forceinline__ float2 level_feat(
        const float2* __restrict__ tbl, float px, float py, float pz, int l) {
    float s  = c_scal[l];
    float sx = px * s, sy = py * s, sz = pz * s;
    float cx = floorf(sx), cy = floorf(sy), cz = floorf(sz);
    float fx = sx - cx, fy = sy - cy, fz = sz - cz;

    unsigned ux = (unsigned)cx, uy = (unsigned)cy, uz = (unsigned)cz;

    unsigned hx0 = ux,               hx1 = ux + 1u;
    unsigned hy0 = uy * 2654435761u, hy1 = (uy + 1u) * 2654435761u;
    unsigned hz0 = uz * 805459861u,  hz1 = (uz + 1u) * 805459861u;

    unsigned base = (unsigned)l * TBL_T;

    unsigned idx[8];
#pragma unroll
    for (int i = 0; i < 8; ++i) {
        unsigned h = ((i & 4) ? hx1 : hx0) ^ ((i & 2) ? hy1 : hy0)
                   ^ ((i & 1) ? hz1 : hz0);
        idx[i] = (h & (TBL_T - 1u)) + base;
    }

    float2 v[8];
#pragma unroll
    for (int i = 0; i < 8; ++i) v[i] = tbl[idx[i]];

    float wx1 = fx, wx0 = 1.f - fx;
    float wy1 = fy, wy0 = 1.f - fy;
    float wz1 = fz, wz0 = 1.f - fz;

    float o0 = 0.f, o1 = 0.f;
#pragma unroll
    for (int i = 0; i < 8; ++i) {
        float w = (((i & 4) ? wx1 : wx0) * ((i & 2) ? wy1 : wy0))
                * ((i & 1) ? wz1 : wz0);
        o0 += v[i].x * w;
        o1 += v[i].y * w;
    }
    return make_float2(o0, o1);
}

// Levels 0..4 fused: combined active-slice footprint ~2.6 MB.
__global__ __launch_bounds__(256) void hashenc_coarse(
        const float* __restrict__ x,
        const float2* __restrict__ tbl,
        float2* __restrict__ ws) {
    unsigned p = blockIdx.x * 256u + threadIdx.x;
    float px = x[p * 3 + 0], py = x[p * 3 + 1], pz = x[p * 3 + 2];
#pragma unroll
    for (int l = 0; l < 5; ++l)
        ws[(size_t)l * NPTS + p] = level_feat(tbl, px, py, pz, l);
}

// One fine level per launch.
__global__ __launch_bounds__(256) void hashenc_level(
        const float* __restrict__ x,
        const float2* __restrict__ tbl,
        float2* __restrict__ ws,
        int l) {
    unsigned p = blockIdx.x * 256u + threadIdx.x;
    float px = x[p * 3 + 0], py = x[p * 3 + 1], pz = x[p * 3 + 2];
    ws[(size_t)l * NPTS + p] = level_feat(tbl, px, py, pz, l);
}

// ws[16][NPTS] float2  ->  out[NPTS][16] float2 (128 B contiguous per point)
__global__ __launch_bounds__(256) void hashenc_transpose(
        const float2* __restrict__ ws,
        float4* __restrict__ out) {
    unsigned p = blockIdx.x * 256u + threadIdx.x;
    float2 v[16];
#pragma unroll
    for (int l = 0; l < 16; ++l) v[l] = ws[(size_t)l * NPTS + p];
    float4* dst = out + (size_t)p * 8u;
#pragma unroll
    for (int q = 0; q < 8; ++q)
        dst[q] = make_float4(v[2 * q].x, v[2 * q].y, v[2 * q + 1].x, v[2 * q + 1].y);
}

// Fallback (ws too small): R2 single-kernel, one thread per point.
__global__ __launch_bounds__(256) void hashenc_mono(
        const float* __restrict__ x,
        const float2* __restrict__ tbl,
        float4* __restrict__ out) {
    unsigned p = blockIdx.x * 256u + threadIdx.x;
    float px = x[p * 3 + 0], py = x[p * 3 + 1], pz = x[p * 3 + 2];
    float o[32];
#pragma unroll
    for (int l = 0; l < 16; ++l) {
        float2 f = level_feat(tbl, px, py, pz, l);
        o[2 * l] = f.x; o[2 * l + 1] = f.y;
        __syncthreads();
    }
    float4* dst = out + (size_t)p * 8u;
#pragma unroll
    for (int q = 0; q < 8; ++q)
        dst[q] = make_float4(o[4 * q], o[4 * q + 1], o[4 * q + 2], o[4 * q + 3]);
}

extern "C" void kernel_launch(void* const* d_in, const int* in_sizes, int n_in,
                              void* d_out, int out_size, void* d_ws, size_t ws_size,
                              hipStream_t stream) {
    const float*  x   = (const float*)d_in[0];
    const float2* tbl = (const float2*)d_in[1];   // [L*T][F=2] floats
    const size_t need = (size_t)16 * NPTS * sizeof(float2);  // 64 MiB

    const unsigned block = 256u;
    const unsigned grid  = NPTS / block;          // 2048 blocks

    if (ws_size >= need) {
        float2* ws = (float2*)d_ws;
        hashenc_coarse<<<grid, block, 0, stream>>>(x, tbl, ws);
        for (int l = 5; l < 16; ++l)
            hashenc_level<<<grid, block, 0, stream>>>(x, tbl, ws, l);
        hashenc_transpose<<<grid, block, 0, stream>>>(ws, (float4*)d_out);
    } else {
        hashenc_mono<<<grid, block, 0, stream>>>(x, tbl, (float4*)d_out);
    }
}